// Round 13
// baseline (1898.186 us; speedup 1.0000x reference)
//
#include <hip/hip_runtime.h>
#include <stdint.h>

// Problem constants
constexpr int NB = 8;      // batch
constexpr int NN = 8192;   // points
constexpr int NS = 1024;   // npoint
constexpr int NK = 32;     // nsample
constexpr int PTOT = NB * NS * NK; // 262144

// f32(0.2*0.2) — matches np f32 compare semantics
#define R2C 0.039999999105930328f

// ---------------- module-global scratch (d_ws is NOT used) ----------------
__device__ unsigned short g_cents[NB * NS];       // FPS-selected indices
__device__ unsigned short g_idx[NB * NS * NK];    // ball-query indices (512 KB)
__device__ float g_stat1[12];                     // mu 3 | S 3x3
__device__ float g_stat2[4160];                   // mu 64 | S 64x64
__device__ float g_stat3[4160];                   // mu 64 | S 64x64
__device__ float g_st2[128];                      // s|t layer2 (published by stat3 blk0)
__device__ float g_st3[256];                      // s|t layer3
__device__ float g_h2[(size_t)PTOT * 64];         // materialized h2 (64 MB)

// ---------------------------------------------------------------- DPP argmax step (packed u64 key)
// key = (d_bits << 32) | ~idx  — d >= 0 so f32 bits are u32-monotone;
// max key == lexicographic (max d, min idx). Identity for no-source lanes: 0
// (any real key has lo = ~idx >= 0xFFFFE000 > 0, so identity always loses).
template<int C, int R>
__device__ __forceinline__ void rstep64(uint32_t& kh, uint32_t& kl){
  uint32_t oh = (uint32_t)__builtin_amdgcn_update_dpp(0, (int)kh, C, R, 0xf, false);
  uint32_t ol = (uint32_t)__builtin_amdgcn_update_dpp(0, (int)kl, C, R, 0xf, false);
  uint64_t o = ((uint64_t)oh << 32) | ol;
  uint64_t k = ((uint64_t)kh << 32) | kl;
  if (o > k){ kh = oh; kl = ol; }
}

// ---------------------------------------------------------------- FPS
// One block per batch — now 1024 threads x 8 points (4 waves/SIMD, was 2).
// Same total VALU work per SIMD; 2x the waves to hide the per-step serial
// latency (DPP chains, LDS partial load, centroid fetch). Memory structure
// unchanged: scalar-LDS cloud (96 KB), parity-buffered packed partials,
// raw lgkm-only barrier, uniform LDS centroid broadcast. Selection bit-exact:
// per-lane ascending-index strict-> scan + global (d,~idx) u64 max.
__global__ __launch_bounds__(1024)
__attribute__((amdgpu_waves_per_eu(4, 4)))
void k_fps(const float* __restrict__ x){
  __shared__ float lp[NN * 3];   // 96 KB xyz triplets (LDS-resident cloud)
  __shared__ uint2 part[32];     // 2 x 16 parity-buffered packed partials
  const int b = blockIdx.x;
  const int t = threadIdx.x;
  const int lane = t & 63;
  const int w = t >> 6;          // 0..15
  const float* xb = x + b * NN * 3;
  float px[8], py[8], pz[8], dd[8];
#pragma unroll
  for (int j = 0; j < 8; j++){
    int p = t + 1024 * j;
    px[j] = xb[p*3+0]; py[j] = xb[p*3+1]; pz[j] = xb[p*3+2];
    dd[j] = 1e10f;
  }
#pragma unroll
  for (int j = 0; j < 8; j++){
    asm volatile("" : "+v"(px[j]), "+v"(py[j]), "+v"(pz[j]));
  }
  for (int i = t; i < NN*3; i += 1024) lp[i] = xb[i];
  float cx = xb[0], cy = xb[1], cz = xb[2];
  if (t == 0) g_cents[b*NS] = 0;
  __syncthreads();
  for (int s = 0; s < NS-1; s++){
    float bv = -1.0f; int bi = 0x7fffffff;
#pragma unroll
    for (int j = 0; j < 8; j++){
      float dx = __fsub_rn(px[j], cx);
      float dy = __fsub_rn(py[j], cy);
      float dz = __fsub_rn(pz[j], cz);
      float d  = __fadd_rn(__fadd_rn(__fmul_rn(dx,dx), __fmul_rn(dy,dy)), __fmul_rn(dz,dz));
      float nd = fminf(dd[j], d);
      dd[j] = nd;
      if (nd > bv){ bv = nd; bi = t + 1024*j; }
    }
    // wave64 argmax on packed key -> lane 63
    uint32_t kh = __float_as_uint(bv);
    uint32_t kl = ~(uint32_t)bi;
    rstep64<0x111, 0xf>(kh, kl);
    rstep64<0x112, 0xf>(kh, kl);
    rstep64<0x114, 0xf>(kh, kl);
    rstep64<0x118, 0xf>(kh, kl);
    rstep64<0x142, 0xa>(kh, kl);
    rstep64<0x143, 0xc>(kh, kl);
    const int pb = (s & 1) << 4;
    if (lane == 63) part[pb + w] = make_uint2(kl, kh);
    // raw barrier: drain LDS only (global g_cents stores ride across freely)
    asm volatile("s_waitcnt lgkmcnt(0)\n\ts_barrier" ::: "memory");
    // all lanes: load the 16 packed partials (broadcast), redundant reduce
    uint2 pr = part[pb + (lane & 15)];
    uint32_t qh = pr.y, ql = pr.x;
    rstep64<0x111, 0xf>(qh, ql);
    rstep64<0x112, 0xf>(qh, ql);
    rstep64<0x114, 0xf>(qh, ql);
    rstep64<0x118, 0xf>(qh, ql);
    int widx = ~__builtin_amdgcn_readlane((int)ql, 15);  // SGPR broadcast
    // uniform centroid fetch from LDS (same-address broadcast)
    const float* cp = lp + widx*3;
    cx = cp[0]; cy = cp[1]; cz = cp[2];
    if (t == 0) g_cents[b*NS + s + 1] = (unsigned short)widx;
  }
}

// ---------------------------------------------------------------- ball query (one wave per group)
// First NK valid indices in ascending order; pad with first valid.
// Also writes the group centroid coords to out (new_x).
__device__ __forceinline__ void ballq_wave(const float* __restrict__ xb,
                                           int c, unsigned short* og,
                                           float* __restrict__ oc){
  const int lane = threadIdx.x & 63;
  const float ax = xb[c*3+0], ay = xb[c*3+1], az = xb[c*3+2];
  if (lane == 0){ oc[0] = ax; oc[1] = ay; oc[2] = az; }
  const float na = __fadd_rn(__fadd_rn(__fmul_rn(ax,ax), __fmul_rn(ay,ay)), __fmul_rn(az,az));
  int cnt = 0, first = -1;
  for (int base = 0; base < NN && cnt < NK; base += 64){
    int n = base + lane;
    float bx = xb[n*3+0], by = xb[n*3+1], bz = xb[n*3+2];
    float dot = __fadd_rn(__fadd_rn(__fmul_rn(ax,bx), __fmul_rn(ay,by)), __fmul_rn(az,bz));
    float nb  = __fadd_rn(__fadd_rn(__fmul_rn(bx,bx), __fmul_rn(by,by)), __fmul_rn(bz,bz));
    float sq  = __fadd_rn(__fadd_rn(__fmul_rn(-2.0f, dot), na), nb);
    bool valid = !(sq > R2C);
    unsigned long long m = __ballot(valid);
    if (first < 0 && m) first = base + (int)__builtin_ctzll(m);
    int pre = __popcll(m & ((1ull << lane) - 1ull));
    int pos = cnt + pre;
    if (valid && pos < NK) og[pos] = (unsigned short)n;
    cnt += __popcll(m);
  }
  if (cnt < NK && lane >= cnt && lane < NK) og[lane] = (unsigned short)first;
}

// 2048 blocks x 4 waves; one group per wave. Writes g_idx + new_x coords.
// Block 0 additionally zeroes the stat accumulators (exact 0 writes,
// stream-ordered before any stat kernel) — replaces the k_zero dispatch.
__global__ __launch_bounds__(256, 4) void k_ballq(const float* __restrict__ x,
                                                  float* __restrict__ out){
  if (blockIdx.x == 0){
    const int tid = threadIdx.x;
    for (int i = tid; i < 4160; i += 256){ g_stat2[i] = 0.f; g_stat3[i] = 0.f; }
    if (tid < 12) g_stat1[tid] = 0.f;
  }
  const int g = blockIdx.x * 4 + (threadIdx.x >> 6);
  const float* xb = x + (g >> 10) * NN * 3;
  ballq_wave(xb, (int)g_cents[g], g_idx + (size_t)g * NK, out + (size_t)g * 3);
}

// ---------------------------------------------------------------- stats of h1 (3-dim)
// 256 blocks x 32 groups each.
__global__ __launch_bounds__(256, 4) void k_stat1(const float* __restrict__ x){
  __shared__ unsigned int idxs_u[512];
  __shared__ float gc[32][3];
  unsigned short* idxs = (unsigned short*)idxs_u;
  const int tid = threadIdx.x;
  const int g0 = blockIdx.x * 32;
  const float* xb = x + (g0 >> 10) * NN * 3;
  for (int i = tid; i < 512; i += 256)
    idxs_u[i] = ((const unsigned int*)(g_idx + (size_t)g0 * NK))[i];
  if (tid < 32){
    int cc = g_cents[g0 + tid];
    gc[tid][0]=xb[cc*3+0]; gc[tid][1]=xb[cc*3+1]; gc[tid][2]=xb[cc*3+2];
  }
  __syncthreads();
  float a[12];
#pragma unroll
  for (int i = 0; i < 12; i++) a[i] = 0.f;
  for (int u = 0; u < 4; u++){
    int sid = u*256 + tid;
    int lg = sid >> 5, kk = sid & 31;
    int ii = idxs[lg*32 + kk];
    float hx = xb[ii*3+0] - gc[lg][0];
    float hy = xb[ii*3+1] - gc[lg][1];
    float hz = xb[ii*3+2] - gc[lg][2];
    a[0]+=hx; a[1]+=hy; a[2]+=hz;
    a[3]+=hx*hx; a[4]+=hx*hy; a[5]+=hx*hz;
    a[6]+=hy*hx; a[7]+=hy*hy; a[8]+=hy*hz;
    a[9]+=hz*hx; a[10]+=hz*hy; a[11]+=hz*hz;
  }
#pragma unroll
  for (int i = 0; i < 12; i++){
#pragma unroll
    for (int off = 32; off > 0; off >>= 1) a[i] += __shfl_down(a[i], off);
  }
  if ((tid & 63) == 0){
#pragma unroll
    for (int i = 0; i < 12; i++) atomicAdd(&g_stat1[i], a[i]);
  }
}

// ---------------------------------------------------------------- stats of h2 (64-dim)
// Prologue computes the layer-1 BN fold (Cin=3) redundantly per block —
// bit-exact replica of the old k_fold(which=0) arithmetic.
// Also materializes h2 to g_h2 for k_stat3/k_final.
__global__ __launch_bounds__(256, 2) void k_stat2(const float* __restrict__ x,
                                                  const float* __restrict__ W1,
                                                  const float* __restrict__ g1,
                                                  const float* __restrict__ be1){
  __shared__ unsigned int idxs_u[512];
  __shared__ float gc[32][3];
  __shared__ float w1t[3][64];
  __shared__ float s1v[64], t1v[64];
  __shared__ float tile[128*68];
  __shared__ float muacc[64];
  __shared__ float ss[9];
  __shared__ float mu1[3];
  __shared__ float partl[256];
  unsigned short* idxs = (unsigned short*)idxs_u;
  const int tid = threadIdx.x;
  const int g0 = blockIdx.x * 32;
  const float* xb = x + (g0 >> 10) * NN * 3;
  const float invP = 1.0f / (float)PTOT;
  for (int i = tid; i < 512; i += 256)
    idxs_u[i] = ((const unsigned int*)(g_idx + (size_t)g0 * NK))[i];
  if (tid < 32){
    int cc = g_cents[g0 + tid];
    gc[tid][0]=xb[cc*3+0]; gc[tid][1]=xb[cc*3+1]; gc[tid][2]=xb[cc*3+2];
  }
  if (tid < 64){
    w1t[0][tid]=W1[tid*3+0]; w1t[1][tid]=W1[tid*3+1]; w1t[2][tid]=W1[tid*3+2];
    muacc[tid]=0.f;
  }
  if (tid < 9) ss[tid] = g_stat1[3 + tid] * invP;
  if (tid < 3) mu1[tid] = g_stat1[tid] * invP;
  __syncthreads();
  // ---- fold1 (same op order as old k_fold which=0)
  {
    const int c = tid % 64, prt = tid / 64;
    float q = 0.f;
    for (int i = prt; i < 3; i += 4){
      float wi = w1t[i][c];
      float r = 0.f;
      for (int j = 0; j < 3; j++) r += ss[i*3 + j] * w1t[j][c];
      q += wi * r;
    }
    partl[tid] = q;
    __syncthreads();
    if (prt == 0){
      for (int p2 = 1; p2 < 4; p2++) q += partl[p2*64 + c];
      float ml = 0.f;
      for (int j = 0; j < 3; j++) ml += w1t[j][c] * mu1[j];
      float var = q - ml*ml;
      float inv = 1.0f / sqrtf(var + 1e-5f);
      float sc = g1[c] * inv;
      s1v[c] = sc; t1v[c] = be1[c] - sc * ml;
    }
  }
  float acc[4][4];
#pragma unroll
  for (int r=0;r<4;r++)
#pragma unroll
    for (int q=0;q<4;q++) acc[r][q]=0.f;
  const int ti = tid & 15, tj = tid >> 4;
  const int pl = tid & 127;
  const int ch0 = (tid >> 7) * 32;
  __syncthreads();
  for (int u = 0; u < 8; u++){
    int sid = u*128 + pl;
    int lg = sid >> 5, kk = sid & 31;
    int ii = idxs[lg*32 + kk];
    float hx = xb[ii*3+0] - gc[lg][0];
    float hy = xb[ii*3+1] - gc[lg][1];
    float hz = xb[ii*3+2] - gc[lg][2];
    float* row = &tile[pl*68 + ch0];
    float* h2g = &g_h2[((size_t)g0*32 + sid)*64 + ch0];
#pragma unroll
    for (int cq = 0; cq < 8; cq++){
      int c = ch0 + cq*4;
      float y0 = fmaf(w1t[0][c+0],hx, fmaf(w1t[1][c+0],hy, w1t[2][c+0]*hz));
      float y1 = fmaf(w1t[0][c+1],hx, fmaf(w1t[1][c+1],hy, w1t[2][c+1]*hz));
      float y2 = fmaf(w1t[0][c+2],hx, fmaf(w1t[1][c+2],hy, w1t[2][c+2]*hz));
      float y3 = fmaf(w1t[0][c+3],hx, fmaf(w1t[1][c+3],hy, w1t[2][c+3]*hz));
      float4 hv;
      hv.x = fmaxf(fmaf(s1v[c+0],y0,t1v[c+0]), 0.f);
      hv.y = fmaxf(fmaf(s1v[c+1],y1,t1v[c+1]), 0.f);
      hv.z = fmaxf(fmaf(s1v[c+2],y2,t1v[c+2]), 0.f);
      hv.w = fmaxf(fmaf(s1v[c+3],y3,t1v[c+3]), 0.f);
      *(float4*)&row[cq*4] = hv;
      *(float4*)&h2g[cq*4] = hv;
    }
    __syncthreads();
    const float4* t4 = (const float4*)tile;
#pragma unroll 4
    for (int p = 0; p < 128; p++){
      float4 av = t4[p*17 + ti];
      float4 bv = t4[p*17 + tj];
      acc[0][0]=fmaf(av.x,bv.x,acc[0][0]); acc[0][1]=fmaf(av.x,bv.y,acc[0][1]);
      acc[0][2]=fmaf(av.x,bv.z,acc[0][2]); acc[0][3]=fmaf(av.x,bv.w,acc[0][3]);
      acc[1][0]=fmaf(av.y,bv.x,acc[1][0]); acc[1][1]=fmaf(av.y,bv.y,acc[1][1]);
      acc[1][2]=fmaf(av.y,bv.z,acc[1][2]); acc[1][3]=fmaf(av.y,bv.w,acc[1][3]);
      acc[2][0]=fmaf(av.z,bv.x,acc[2][0]); acc[2][1]=fmaf(av.z,bv.y,acc[2][1]);
      acc[2][2]=fmaf(av.z,bv.z,acc[2][2]); acc[2][3]=fmaf(av.z,bv.w,acc[2][3]);
      acc[3][0]=fmaf(av.w,bv.x,acc[3][0]); acc[3][1]=fmaf(av.w,bv.y,acc[3][1]);
      acc[3][2]=fmaf(av.w,bv.z,acc[3][2]); acc[3][3]=fmaf(av.w,bv.w,acc[3][3]);
    }
    if (tid < 64){
      float m = 0.f;
      for (int p = 0; p < 128; p++) m += tile[p*68 + tid];
      muacc[tid] += m;
    }
    __syncthreads();
  }
  if (tid < 64) atomicAdd(&g_stat2[tid], muacc[tid]);
#pragma unroll
  for (int r=0;r<4;r++)
#pragma unroll
    for (int q=0;q<4;q++)
      atomicAdd(&g_stat2[64 + (ti*4+r)*64 + (tj*4+q)], acc[r][q]);
}

// ---------------------------------------------------------------- stats of h3 (64-dim)
// Prologue computes the layer-2 BN fold (Cin=64) redundantly per block —
// bit-exact replica of the old k_fold(which=1); block 0 publishes g_st2
// for k_final. The tile buffer is aliased as fold scratch (fully consumed
// before the main loop overwrites it). Reads materialized h2 (coalesced).
__global__ __launch_bounds__(256, 2) void k_stat3(const float* __restrict__ W2,
                                                  const float* __restrict__ g2,
                                                  const float* __restrict__ be2){
  __shared__ float s2v[64], t2v[64];
  __shared__ float w2f[4096];
  __shared__ float tile[128*68];
  __shared__ float muacc[64];
  __shared__ float mu2[64];
  __shared__ float partl[256];
  const int tid = threadIdx.x;
  const int g0 = blockIdx.x * 32;
  const float invP = 1.0f / (float)PTOT;
  // ---- fold2 (same op order as old k_fold which=1); tile aliased as scratch
  {
    float* s_l = tile;             // 64*65 floats
    float* w_l = tile + 64*65;     // 64*65 floats (8320 <= 8704 total)
    for (int i = tid; i < 4096; i += 256) w_l[(i>>6)*65 + (i&63)] = W2[i];
    for (int i = tid; i < 4096; i += 256) s_l[(i>>6)*65 + (i&63)] = g_stat2[64 + i] * invP;
    if (tid < 64){ mu2[tid] = g_stat2[tid] * invP; muacc[tid] = 0.f; }
#pragma unroll
    for (int e = 0; e < 16; e++) w2f[tid + e*256] = W2[tid + e*256];
    __syncthreads();
    const int c = tid % 64, prt = tid / 64;
    float q = 0.f;
    for (int i = prt; i < 64; i += 4){
      float wi = w_l[c*65 + i];
      float r = 0.f;
      for (int j = 0; j < 64; j++)
        r += s_l[i*65 + j] * w_l[c*65 + j];
      q += wi * r;
    }
    partl[tid] = q;
    __syncthreads();
    if (prt == 0){
      for (int p2 = 1; p2 < 4; p2++) q += partl[p2*64 + c];
      float ml = 0.f;
      for (int j = 0; j < 64; j++) ml += w_l[c*65 + j] * mu2[j];
      float var = q - ml*ml;
      float inv = 1.0f / sqrtf(var + 1e-5f);
      float sc = g2[c] * inv;
      float tc = be2[c] - sc * ml;
      s2v[c] = sc; t2v[c] = tc;
      if (blockIdx.x == 0){ g_st2[c] = sc; g_st2[64 + c] = tc; }
    }
    __syncthreads();
  }
  float acc[4][4];
#pragma unroll
  for (int r=0;r<4;r++)
#pragma unroll
    for (int q=0;q<4;q++) acc[r][q]=0.f;
  const int ti = tid & 15, tj = tid >> 4;
  const int pl = tid & 127;
  const int ch0 = (tid >> 7) * 32;
  for (int u = 0; u < 8; u++){
    int sid = u*128 + pl;
    float h2r[64];
    const float4* h2p = (const float4*)&g_h2[((size_t)g0*32 + sid)*64];
#pragma unroll
    for (int j4 = 0; j4 < 16; j4++){
      float4 v = h2p[j4];
      h2r[j4*4+0]=v.x; h2r[j4*4+1]=v.y; h2r[j4*4+2]=v.z; h2r[j4*4+3]=v.w;
    }
    float* row = &tile[pl*68];
    for (int c = ch0; c < ch0 + 32; c++){
      const float4* wr = (const float4*)&w2f[c*64];
      float y = 0.f;
#pragma unroll
      for (int j4 = 0; j4 < 16; j4++){
        float4 wv = wr[j4];
        y = fmaf(wv.x, h2r[j4*4+0], y);
        y = fmaf(wv.y, h2r[j4*4+1], y);
        y = fmaf(wv.z, h2r[j4*4+2], y);
        y = fmaf(wv.w, h2r[j4*4+3], y);
      }
      row[c] = fmaxf(fmaf(s2v[c], y, t2v[c]), 0.f);
    }
    __syncthreads();
    const float4* t4 = (const float4*)tile;
#pragma unroll 4
    for (int p = 0; p < 128; p++){
      float4 av = t4[p*17 + ti];
      float4 bv = t4[p*17 + tj];
      acc[0][0]=fmaf(av.x,bv.x,acc[0][0]); acc[0][1]=fmaf(av.x,bv.y,acc[0][1]);
      acc[0][2]=fmaf(av.x,bv.z,acc[0][2]); acc[0][3]=fmaf(av.x,bv.w,acc[0][3]);
      acc[1][0]=fmaf(av.y,bv.x,acc[1][0]); acc[1][1]=fmaf(av.y,bv.y,acc[1][1]);
      acc[1][2]=fmaf(av.y,bv.z,acc[1][2]); acc[1][3]=fmaf(av.y,bv.w,acc[1][3]);
      acc[2][0]=fmaf(av.z,bv.x,acc[2][0]); acc[2][1]=fmaf(av.z,bv.y,acc[2][1]);
      acc[2][2]=fmaf(av.z,bv.z,acc[2][2]); acc[2][3]=fmaf(av.z,bv.w,acc[2][3]);
      acc[3][0]=fmaf(av.w,bv.x,acc[3][0]); acc[3][1]=fmaf(av.w,bv.y,acc[3][1]);
      acc[3][2]=fmaf(av.w,bv.z,acc[3][2]); acc[3][3]=fmaf(av.w,bv.w,acc[3][3]);
    }
    if (tid < 64){
      float m = 0.f;
      for (int p = 0; p < 128; p++) m += tile[p*68 + tid];
      muacc[tid] += m;
    }
    __syncthreads();
  }
  if (tid < 64) atomicAdd(&g_stat3[tid], muacc[tid]);
#pragma unroll
  for (int r=0;r<4;r++)
#pragma unroll
    for (int q=0;q<4;q++)
      atomicAdd(&g_stat3[64 + (ti*4+r)*64 + (tj*4+q)], acc[r][q]);
}

// ---------------------------------------------------------------- layer-3 BN fold, 8-way split
// Block b computes channels [b*16, b*16+16) with the ORIGINAL per-channel
// partial-sum order (prt in {0,1}, i stride 2) — bit-exact vs single-block.
__global__ __launch_bounds__(256, 4) void k_fold3(const float* __restrict__ W3,
                                                  const float* __restrict__ g3,
                                                  const float* __restrict__ be3){
  __shared__ float s_l[64*65];
  __shared__ float w_l[16*65];
  __shared__ float mu[64];
  __shared__ float partl[32];
  const int tid = threadIdx.x;
  const int cb = blockIdx.x * 16;
  const float invP = 1.0f / (float)PTOT;
  for (int i = tid; i < 4096; i += 256) s_l[(i>>6)*65 + (i&63)] = g_stat3[64 + i] * invP;
  for (int i = tid; i < 16*64; i += 256) w_l[(i>>6)*65 + (i&63)] = W3[(cb + (i>>6))*64 + (i&63)];
  if (tid < 64) mu[tid] = g_stat3[tid] * invP;
  __syncthreads();
  if (tid < 32){
    const int cl = tid & 15, prt = tid >> 4;
    float q = 0.f;
    for (int i = prt; i < 64; i += 2){
      float wi = w_l[cl*65 + i];
      float r = 0.f;
      for (int j = 0; j < 64; j++)
        r += s_l[i*65 + j] * w_l[cl*65 + j];
      q += wi * r;
    }
    partl[tid] = q;
  }
  __syncthreads();
  if (tid < 16){
    const int cl = tid;
    const int c = cb + cl;
    float q = partl[cl] + partl[16 + cl];   // q(prt0) + q(prt1), original order
    float ml = 0.f;
    for (int j = 0; j < 64; j++) ml += w_l[cl*65 + j] * mu[j];
    float var = q - ml*ml;
    float inv = 1.0f / sqrtf(var + 1e-5f);
    float sc = g3[c] * inv;
    float tc = be3[c] - sc * ml;
    g_st3[c] = sc; g_st3[128 + c] = tc;
  }
}

// ---------------------------------------------------------------- final: layers 2-3 + maxpool
// Reads materialized h2 (coalesced); 2048 blocks x 4 groups each.
__global__ __launch_bounds__(256, 2) void k_final(const float* __restrict__ W2,
    const float* __restrict__ W3,
    float* __restrict__ out){
  __shared__ float s2v[64], t2v[64], s3v[128], t3v[128];
  __shared__ float h2t[32*68];
  __shared__ float h3t[32*68];
  __shared__ float mx[2][128];
  const int tid = threadIdx.x;
  const int g0 = blockIdx.x * 4;
  if (tid < 64){
    s2v[tid]=g_st2[tid]; t2v[tid]=g_st2[64+tid];
  }
  if (tid < 128){ s3v[tid]=g_st3[tid]; t3v[tid]=g_st3[128+tid]; }
  __syncthreads();
  for (int gi = 0; gi < 4; gi++){
    // stage h2 (32 x 64) — coalesced read of materialized values
    {
      const float* src = &g_h2[(size_t)(g0 + gi) * 32 * 64];
#pragma unroll
      for (int u = 0; u < 8; u++){
        int v = tid + u * 256;
        int kk = v >> 6, c = v & 63;
        h2t[kk*68 + c] = src[v];
      }
    }
    __syncthreads();
    // layer 2: thread owns channel c2, 8 k's
    {
      const int c2 = tid & 63, kq = tid >> 6;
      float wv2[64];
      const float4* wrow = (const float4*)(W2 + c2*64);
#pragma unroll
      for (int q = 0; q < 16; q++){
        float4 uv = wrow[q];
        wv2[q*4+0]=uv.x; wv2[q*4+1]=uv.y; wv2[q*4+2]=uv.z; wv2[q*4+3]=uv.w;
      }
#pragma unroll
      for (int k2 = 0; k2 < 8; k2++){
        int kk = kq*8 + k2;
        const float4* hr = (const float4*)&h2t[kk*68];
        float y = 0.f;
#pragma unroll
        for (int j4 = 0; j4 < 16; j4++){
          float4 hv = hr[j4];
          y = fmaf(wv2[j4*4+0], hv.x, y);
          y = fmaf(wv2[j4*4+1], hv.y, y);
          y = fmaf(wv2[j4*4+2], hv.z, y);
          y = fmaf(wv2[j4*4+3], hv.w, y);
        }
        h3t[kk*68 + c2] = fmaxf(fmaf(s2v[c2], y, t2v[c2]), 0.f);
      }
    }
    __syncthreads();
    // layer 3 + max over k
    {
      const int c3 = tid & 127, half = tid >> 7;
      float wv3[64];
      const float4* wrow = (const float4*)(W3 + c3*64);
#pragma unroll
      for (int q = 0; q < 16; q++){
        float4 uv = wrow[q];
        wv3[q*4+0]=uv.x; wv3[q*4+1]=uv.y; wv3[q*4+2]=uv.z; wv3[q*4+3]=uv.w;
      }
      float m = -1e30f;
#pragma unroll
      for (int k2 = 0; k2 < 16; k2++){
        int kk = half*16 + k2;
        const float4* hr = (const float4*)&h3t[kk*68];
        float y = 0.f;
#pragma unroll
        for (int j4 = 0; j4 < 16; j4++){
          float4 hv = hr[j4];
          y = fmaf(wv3[j4*4+0], hv.x, y);
          y = fmaf(wv3[j4*4+1], hv.y, y);
          y = fmaf(wv3[j4*4+2], hv.z, y);
          y = fmaf(wv3[j4*4+3], hv.w, y);
        }
        float h4 = fmaxf(fmaf(s3v[c3], y, t3v[c3]), 0.f);
        m = fmaxf(m, h4);
      }
      mx[half][c3] = m;
    }
    __syncthreads();
    if (tid < 128){
      float m = fmaxf(mx[0][tid], mx[1][tid]);
      out[24576 + ((g0 + gi) << 7) + tid] = m; // f32 feature output
    }
    __syncthreads();
  }
}

// ---------------------------------------------------------------- launch
extern "C" void kernel_launch(void* const* d_in, const int* in_sizes, int n_in,
                              void* d_out, int out_size, void* d_ws, size_t ws_size,
                              hipStream_t stream){
  const float* x   = (const float*)d_in[0];
  const float* W1  = (const float*)d_in[1];
  const float* g1  = (const float*)d_in[3];
  const float* be1 = (const float*)d_in[4];
  const float* W2  = (const float*)d_in[5];
  const float* g2  = (const float*)d_in[7];
  const float* be2 = (const float*)d_in[8];
  const float* W3  = (const float*)d_in[9];
  const float* g3  = (const float*)d_in[11];
  const float* be3 = (const float*)d_in[12];
  float* out = (float*)d_out;
  (void)d_ws; (void)ws_size; (void)in_sizes; (void)n_in; (void)out_size;

  k_fps<<<NB, 1024, 0, stream>>>(x);
  k_ballq<<<(NB*NS)/4, 256, 0, stream>>>(x, out);
  k_stat1<<<256, 256, 0, stream>>>(x);
  k_stat2<<<256, 256, 0, stream>>>(x, W1, g1, be1);
  k_stat3<<<256, 256, 0, stream>>>(W2, g2, be2);
  k_fold3<<<8, 256, 0, stream>>>(W3, g3, be3);
  k_final<<<2048, 256, 0, stream>>>(W2, W3, out);
}

// Round 14
// 1683.820 us; speedup vs baseline: 1.1273x; 1.1273x over previous
//
#include <hip/hip_runtime.h>
#include <stdint.h>

// Problem constants
constexpr int NB = 8;      // batch
constexpr int NN = 8192;   // points
constexpr int NS = 1024;   // npoint
constexpr int NK = 32;     // nsample
constexpr int PTOT = NB * NS * NK; // 262144

// f32(0.2*0.2) — matches np f32 compare semantics
#define R2C 0.039999999105930328f

// ---------------- module-global scratch (d_ws is NOT used) ----------------
__device__ unsigned short g_cents[NB * NS];       // FPS-selected indices
__device__ unsigned short g_idx[NB * NS * NK];    // ball-query indices (512 KB)
__device__ float g_stat1[12];                     // mu 3 | S 3x3
__device__ float g_stat2[4160];                   // mu 64 | S 64x64
__device__ float g_stat3[4160];                   // mu 64 | S 64x64
__device__ float g_st2[128];                      // s|t layer2 (published by stat3 blk0)
__device__ float g_st3[256];                      // s|t layer3
__device__ float g_h2[(size_t)PTOT * 64];         // materialized h2 (64 MB)

// ---------------------------------------------------------------- DPP argmax step (packed u64 key)
// key = (d_bits << 32) | ~idx  — d >= 0 so f32 bits are u32-monotone;
// max key == lexicographic (max d, min idx). Identity for no-source lanes: 0
// (any real key has lo = ~idx >= 0xFFFFE000 > 0, so identity always loses).
template<int C, int R>
__device__ __forceinline__ void rstep64(uint32_t& kh, uint32_t& kl){
  uint32_t oh = (uint32_t)__builtin_amdgcn_update_dpp(0, (int)kh, C, R, 0xf, false);
  uint32_t ol = (uint32_t)__builtin_amdgcn_update_dpp(0, (int)kl, C, R, 0xf, false);
  uint64_t o = ((uint64_t)oh << 32) | ol;
  uint64_t k = ((uint64_t)kh << 32) | kl;
  if (o > k){ kh = oh; kl = ol; }
}

// ---------------------------------------------------------------- FPS
// One block per batch. 512 threads x 16 points, coords pinned in VGPRs.
// Point cloud mirrored in LDS (96 KB); uniform-address centroid broadcast;
// single raw lgkm-only s_barrier per step.
// EXACT copy of the measured-889 µs kernel — FROZEN; 7/8 perturbations
// (float4 layout, chain-split, scalar rstep, pk-f32, candidate prefetch x2,
// 1024-thread shape) all regressed. Do not touch.
__global__ __launch_bounds__(512)
__attribute__((amdgpu_waves_per_eu(2, 2)))
void k_fps(const float* __restrict__ x){
  __shared__ float lp[NN * 3];   // 96 KB xyz triplets (LDS-resident cloud)
  __shared__ uint2 part[16];     // 2 x 8 parity-buffered packed partials
  const int b = blockIdx.x;
  const int t = threadIdx.x;
  const int lane = t & 63;
  const int w = t >> 6;
  const float* xb = x + b * NN * 3;
  float px[16], py[16], pz[16], dd[16];
#pragma unroll
  for (int j = 0; j < 16; j++){
    int p = t + 512 * j;
    px[j] = xb[p*3+0]; py[j] = xb[p*3+1]; pz[j] = xb[p*3+2];
    dd[j] = 1e10f;
  }
#pragma unroll
  for (int j = 0; j < 16; j++){
    asm volatile("" : "+v"(px[j]), "+v"(py[j]), "+v"(pz[j]));
  }
  for (int i = t; i < NN*3; i += 512) lp[i] = xb[i];
  float cx = xb[0], cy = xb[1], cz = xb[2];
  if (t == 0) g_cents[b*NS] = 0;
  __syncthreads();
  for (int s = 0; s < NS-1; s++){
    float bv = -1.0f; int bi = 0x7fffffff;
#pragma unroll
    for (int j = 0; j < 16; j++){
      float dx = __fsub_rn(px[j], cx);
      float dy = __fsub_rn(py[j], cy);
      float dz = __fsub_rn(pz[j], cz);
      float d  = __fadd_rn(__fadd_rn(__fmul_rn(dx,dx), __fmul_rn(dy,dy)), __fmul_rn(dz,dz));
      float nd = fminf(dd[j], d);
      dd[j] = nd;
      if (nd > bv){ bv = nd; bi = t + 512*j; }
    }
    // wave64 argmax on packed key -> lane 63
    uint32_t kh = __float_as_uint(bv);
    uint32_t kl = ~(uint32_t)bi;
    rstep64<0x111, 0xf>(kh, kl);
    rstep64<0x112, 0xf>(kh, kl);
    rstep64<0x114, 0xf>(kh, kl);
    rstep64<0x118, 0xf>(kh, kl);
    rstep64<0x142, 0xa>(kh, kl);
    rstep64<0x143, 0xc>(kh, kl);
    const int pb = (s & 1) << 3;
    if (lane == 63) part[pb + w] = make_uint2(kl, kh);
    // raw barrier: drain LDS only (global g_cents stores ride across freely)
    asm volatile("s_waitcnt lgkmcnt(0)\n\ts_barrier" ::: "memory");
    // all lanes: load the 8 packed partials (broadcast), redundant reduce
    uint2 pr = part[pb + (lane & 7)];
    uint32_t qh = pr.y, ql = pr.x;
    rstep64<0x111, 0xf>(qh, ql);
    rstep64<0x112, 0xf>(qh, ql);
    rstep64<0x114, 0xf>(qh, ql);
    int widx = ~__builtin_amdgcn_readlane((int)ql, 7);  // SGPR broadcast
    // uniform centroid fetch from LDS (same-address broadcast)
    const float* cp = lp + widx*3;
    cx = cp[0]; cy = cp[1]; cz = cp[2];
    if (t == 0) g_cents[b*NS + s + 1] = (unsigned short)widx;
  }
}

// ---------------------------------------------------------------- ball query (one wave per group)
// First NK valid indices in ascending order; pad with first valid.
// Also writes the group centroid coords to out (new_x).
__device__ __forceinline__ void ballq_wave(const float* __restrict__ xb,
                                           int c, unsigned short* og,
                                           float* __restrict__ oc){
  const int lane = threadIdx.x & 63;
  const float ax = xb[c*3+0], ay = xb[c*3+1], az = xb[c*3+2];
  if (lane == 0){ oc[0] = ax; oc[1] = ay; oc[2] = az; }
  const float na = __fadd_rn(__fadd_rn(__fmul_rn(ax,ax), __fmul_rn(ay,ay)), __fmul_rn(az,az));
  int cnt = 0, first = -1;
  for (int base = 0; base < NN && cnt < NK; base += 64){
    int n = base + lane;
    float bx = xb[n*3+0], by = xb[n*3+1], bz = xb[n*3+2];
    float dot = __fadd_rn(__fadd_rn(__fmul_rn(ax,bx), __fmul_rn(ay,by)), __fmul_rn(az,bz));
    float nb  = __fadd_rn(__fadd_rn(__fmul_rn(bx,bx), __fmul_rn(by,by)), __fmul_rn(bz,bz));
    float sq  = __fadd_rn(__fadd_rn(__fmul_rn(-2.0f, dot), na), nb);
    bool valid = !(sq > R2C);
    unsigned long long m = __ballot(valid);
    if (first < 0 && m) first = base + (int)__builtin_ctzll(m);
    int pre = __popcll(m & ((1ull << lane) - 1ull));
    int pos = cnt + pre;
    if (valid && pos < NK) og[pos] = (unsigned short)n;
    cnt += __popcll(m);
  }
  if (cnt < NK && lane >= cnt && lane < NK) og[lane] = (unsigned short)first;
}

// 2048 blocks x 4 waves; one group per wave. Writes g_idx + new_x coords.
// Block 0 additionally zeroes the stat accumulators (exact 0 writes,
// stream-ordered before any stat kernel) — replaces the k_zero dispatch.
__global__ __launch_bounds__(256, 4) void k_ballq(const float* __restrict__ x,
                                                  float* __restrict__ out){
  if (blockIdx.x == 0){
    const int tid = threadIdx.x;
    for (int i = tid; i < 4160; i += 256){ g_stat2[i] = 0.f; g_stat3[i] = 0.f; }
    if (tid < 12) g_stat1[tid] = 0.f;
  }
  const int g = blockIdx.x * 4 + (threadIdx.x >> 6);
  const float* xb = x + (g >> 10) * NN * 3;
  ballq_wave(xb, (int)g_cents[g], g_idx + (size_t)g * NK, out + (size_t)g * 3);
}

// ---------------------------------------------------------------- stats of h1 (3-dim)
// 256 blocks x 32 groups each.
__global__ __launch_bounds__(256, 4) void k_stat1(const float* __restrict__ x){
  __shared__ unsigned int idxs_u[512];
  __shared__ float gc[32][3];
  unsigned short* idxs = (unsigned short*)idxs_u;
  const int tid = threadIdx.x;
  const int g0 = blockIdx.x * 32;
  const float* xb = x + (g0 >> 10) * NN * 3;
  for (int i = tid; i < 512; i += 256)
    idxs_u[i] = ((const unsigned int*)(g_idx + (size_t)g0 * NK))[i];
  if (tid < 32){
    int cc = g_cents[g0 + tid];
    gc[tid][0]=xb[cc*3+0]; gc[tid][1]=xb[cc*3+1]; gc[tid][2]=xb[cc*3+2];
  }
  __syncthreads();
  float a[12];
#pragma unroll
  for (int i = 0; i < 12; i++) a[i] = 0.f;
  for (int u = 0; u < 4; u++){
    int sid = u*256 + tid;
    int lg = sid >> 5, kk = sid & 31;
    int ii = idxs[lg*32 + kk];
    float hx = xb[ii*3+0] - gc[lg][0];
    float hy = xb[ii*3+1] - gc[lg][1];
    float hz = xb[ii*3+2] - gc[lg][2];
    a[0]+=hx; a[1]+=hy; a[2]+=hz;
    a[3]+=hx*hx; a[4]+=hx*hy; a[5]+=hx*hz;
    a[6]+=hy*hx; a[7]+=hy*hy; a[8]+=hy*hz;
    a[9]+=hz*hx; a[10]+=hz*hy; a[11]+=hz*hz;
  }
#pragma unroll
  for (int i = 0; i < 12; i++){
#pragma unroll
    for (int off = 32; off > 0; off >>= 1) a[i] += __shfl_down(a[i], off);
  }
  if ((tid & 63) == 0){
#pragma unroll
    for (int i = 0; i < 12; i++) atomicAdd(&g_stat1[i], a[i]);
  }
}

// ---------------------------------------------------------------- stats of h2 (64-dim)
// Prologue computes the layer-1 BN fold (Cin=3) redundantly per block —
// bit-exact replica of the old k_fold(which=0) arithmetic.
// Also materializes h2 to g_h2 for k_stat3/k_final.
__global__ __launch_bounds__(256, 2) void k_stat2(const float* __restrict__ x,
                                                  const float* __restrict__ W1,
                                                  const float* __restrict__ g1,
                                                  const float* __restrict__ be1){
  __shared__ unsigned int idxs_u[512];
  __shared__ float gc[32][3];
  __shared__ float w1t[3][64];
  __shared__ float s1v[64], t1v[64];
  __shared__ float tile[128*68];
  __shared__ float muacc[64];
  __shared__ float ss[9];
  __shared__ float mu1[3];
  __shared__ float partl[256];
  unsigned short* idxs = (unsigned short*)idxs_u;
  const int tid = threadIdx.x;
  const int g0 = blockIdx.x * 32;
  const float* xb = x + (g0 >> 10) * NN * 3;
  const float invP = 1.0f / (float)PTOT;
  for (int i = tid; i < 512; i += 256)
    idxs_u[i] = ((const unsigned int*)(g_idx + (size_t)g0 * NK))[i];
  if (tid < 32){
    int cc = g_cents[g0 + tid];
    gc[tid][0]=xb[cc*3+0]; gc[tid][1]=xb[cc*3+1]; gc[tid][2]=xb[cc*3+2];
  }
  if (tid < 64){
    w1t[0][tid]=W1[tid*3+0]; w1t[1][tid]=W1[tid*3+1]; w1t[2][tid]=W1[tid*3+2];
    muacc[tid]=0.f;
  }
  if (tid < 9) ss[tid] = g_stat1[3 + tid] * invP;
  if (tid < 3) mu1[tid] = g_stat1[tid] * invP;
  __syncthreads();
  // ---- fold1 (same op order as old k_fold which=0)
  {
    const int c = tid % 64, prt = tid / 64;
    float q = 0.f;
    for (int i = prt; i < 3; i += 4){
      float wi = w1t[i][c];
      float r = 0.f;
      for (int j = 0; j < 3; j++) r += ss[i*3 + j] * w1t[j][c];
      q += wi * r;
    }
    partl[tid] = q;
    __syncthreads();
    if (prt == 0){
      for (int p2 = 1; p2 < 4; p2++) q += partl[p2*64 + c];
      float ml = 0.f;
      for (int j = 0; j < 3; j++) ml += w1t[j][c] * mu1[j];
      float var = q - ml*ml;
      float inv = 1.0f / sqrtf(var + 1e-5f);
      float sc = g1[c] * inv;
      s1v[c] = sc; t1v[c] = be1[c] - sc * ml;
    }
  }
  float acc[4][4];
#pragma unroll
  for (int r=0;r<4;r++)
#pragma unroll
    for (int q=0;q<4;q++) acc[r][q]=0.f;
  const int ti = tid & 15, tj = tid >> 4;
  const int pl = tid & 127;
  const int ch0 = (tid >> 7) * 32;
  __syncthreads();
  for (int u = 0; u < 8; u++){
    int sid = u*128 + pl;
    int lg = sid >> 5, kk = sid & 31;
    int ii = idxs[lg*32 + kk];
    float hx = xb[ii*3+0] - gc[lg][0];
    float hy = xb[ii*3+1] - gc[lg][1];
    float hz = xb[ii*3+2] - gc[lg][2];
    float* row = &tile[pl*68 + ch0];
    float* h2g = &g_h2[((size_t)g0*32 + sid)*64 + ch0];
#pragma unroll
    for (int cq = 0; cq < 8; cq++){
      int c = ch0 + cq*4;
      float y0 = fmaf(w1t[0][c+0],hx, fmaf(w1t[1][c+0],hy, w1t[2][c+0]*hz));
      float y1 = fmaf(w1t[0][c+1],hx, fmaf(w1t[1][c+1],hy, w1t[2][c+1]*hz));
      float y2 = fmaf(w1t[0][c+2],hx, fmaf(w1t[1][c+2],hy, w1t[2][c+2]*hz));
      float y3 = fmaf(w1t[0][c+3],hx, fmaf(w1t[1][c+3],hy, w1t[2][c+3]*hz));
      float4 hv;
      hv.x = fmaxf(fmaf(s1v[c+0],y0,t1v[c+0]), 0.f);
      hv.y = fmaxf(fmaf(s1v[c+1],y1,t1v[c+1]), 0.f);
      hv.z = fmaxf(fmaf(s1v[c+2],y2,t1v[c+2]), 0.f);
      hv.w = fmaxf(fmaf(s1v[c+3],y3,t1v[c+3]), 0.f);
      *(float4*)&row[cq*4] = hv;
      *(float4*)&h2g[cq*4] = hv;
    }
    __syncthreads();
    const float4* t4 = (const float4*)tile;
#pragma unroll 4
    for (int p = 0; p < 128; p++){
      float4 av = t4[p*17 + ti];
      float4 bv = t4[p*17 + tj];
      acc[0][0]=fmaf(av.x,bv.x,acc[0][0]); acc[0][1]=fmaf(av.x,bv.y,acc[0][1]);
      acc[0][2]=fmaf(av.x,bv.z,acc[0][2]); acc[0][3]=fmaf(av.x,bv.w,acc[0][3]);
      acc[1][0]=fmaf(av.y,bv.x,acc[1][0]); acc[1][1]=fmaf(av.y,bv.y,acc[1][1]);
      acc[1][2]=fmaf(av.y,bv.z,acc[1][2]); acc[1][3]=fmaf(av.y,bv.w,acc[1][3]);
      acc[2][0]=fmaf(av.z,bv.x,acc[2][0]); acc[2][1]=fmaf(av.z,bv.y,acc[2][1]);
      acc[2][2]=fmaf(av.z,bv.z,acc[2][2]); acc[2][3]=fmaf(av.z,bv.w,acc[2][3]);
      acc[3][0]=fmaf(av.w,bv.x,acc[3][0]); acc[3][1]=fmaf(av.w,bv.y,acc[3][1]);
      acc[3][2]=fmaf(av.w,bv.z,acc[3][2]); acc[3][3]=fmaf(av.w,bv.w,acc[3][3]);
    }
    if (tid < 64){
      float m = 0.f;
      for (int p = 0; p < 128; p++) m += tile[p*68 + tid];
      muacc[tid] += m;
    }
    __syncthreads();
  }
  if (tid < 64) atomicAdd(&g_stat2[tid], muacc[tid]);
#pragma unroll
  for (int r=0;r<4;r++)
#pragma unroll
    for (int q=0;q<4;q++)
      atomicAdd(&g_stat2[64 + (ti*4+r)*64 + (tj*4+q)], acc[r][q]);
}

// ---------------------------------------------------------------- stats of h3 (64-dim)
// Prologue computes the layer-2 BN fold (Cin=64) redundantly per block —
// bit-exact replica of the old k_fold(which=1); block 0 publishes g_st2
// for k_final. The tile buffer is aliased as fold scratch (fully consumed
// before the main loop overwrites it). Reads materialized h2 (coalesced).
__global__ __launch_bounds__(256, 2) void k_stat3(const float* __restrict__ W2,
                                                  const float* __restrict__ g2,
                                                  const float* __restrict__ be2){
  __shared__ float s2v[64], t2v[64];
  __shared__ float w2f[4096];
  __shared__ float tile[128*68];
  __shared__ float muacc[64];
  __shared__ float mu2[64];
  __shared__ float partl[256];
  const int tid = threadIdx.x;
  const int g0 = blockIdx.x * 32;
  const float invP = 1.0f / (float)PTOT;
  // ---- fold2 (same op order as old k_fold which=1); tile aliased as scratch
  {
    float* s_l = tile;             // 64*65 floats
    float* w_l = tile + 64*65;     // 64*65 floats (8320 <= 8704 total)
    for (int i = tid; i < 4096; i += 256) w_l[(i>>6)*65 + (i&63)] = W2[i];
    for (int i = tid; i < 4096; i += 256) s_l[(i>>6)*65 + (i&63)] = g_stat2[64 + i] * invP;
    if (tid < 64){ mu2[tid] = g_stat2[tid] * invP; muacc[tid] = 0.f; }
#pragma unroll
    for (int e = 0; e < 16; e++) w2f[tid + e*256] = W2[tid + e*256];
    __syncthreads();
    const int c = tid % 64, prt = tid / 64;
    float q = 0.f;
    for (int i = prt; i < 64; i += 4){
      float wi = w_l[c*65 + i];
      float r = 0.f;
      for (int j = 0; j < 64; j++)
        r += s_l[i*65 + j] * w_l[c*65 + j];
      q += wi * r;
    }
    partl[tid] = q;
    __syncthreads();
    if (prt == 0){
      for (int p2 = 1; p2 < 4; p2++) q += partl[p2*64 + c];
      float ml = 0.f;
      for (int j = 0; j < 64; j++) ml += w_l[c*65 + j] * mu2[j];
      float var = q - ml*ml;
      float inv = 1.0f / sqrtf(var + 1e-5f);
      float sc = g2[c] * inv;
      float tc = be2[c] - sc * ml;
      s2v[c] = sc; t2v[c] = tc;
      if (blockIdx.x == 0){ g_st2[c] = sc; g_st2[64 + c] = tc; }
    }
    __syncthreads();
  }
  float acc[4][4];
#pragma unroll
  for (int r=0;r<4;r++)
#pragma unroll
    for (int q=0;q<4;q++) acc[r][q]=0.f;
  const int ti = tid & 15, tj = tid >> 4;
  const int pl = tid & 127;
  const int ch0 = (tid >> 7) * 32;
  for (int u = 0; u < 8; u++){
    int sid = u*128 + pl;
    float h2r[64];
    const float4* h2p = (const float4*)&g_h2[((size_t)g0*32 + sid)*64];
#pragma unroll
    for (int j4 = 0; j4 < 16; j4++){
      float4 v = h2p[j4];
      h2r[j4*4+0]=v.x; h2r[j4*4+1]=v.y; h2r[j4*4+2]=v.z; h2r[j4*4+3]=v.w;
    }
    float* row = &tile[pl*68];
    for (int c = ch0; c < ch0 + 32; c++){
      const float4* wr = (const float4*)&w2f[c*64];
      float y = 0.f;
#pragma unroll
      for (int j4 = 0; j4 < 16; j4++){
        float4 wv = wr[j4];
        y = fmaf(wv.x, h2r[j4*4+0], y);
        y = fmaf(wv.y, h2r[j4*4+1], y);
        y = fmaf(wv.z, h2r[j4*4+2], y);
        y = fmaf(wv.w, h2r[j4*4+3], y);
      }
      row[c] = fmaxf(fmaf(s2v[c], y, t2v[c]), 0.f);
    }
    __syncthreads();
    const float4* t4 = (const float4*)tile;
#pragma unroll 4
    for (int p = 0; p < 128; p++){
      float4 av = t4[p*17 + ti];
      float4 bv = t4[p*17 + tj];
      acc[0][0]=fmaf(av.x,bv.x,acc[0][0]); acc[0][1]=fmaf(av.x,bv.y,acc[0][1]);
      acc[0][2]=fmaf(av.x,bv.z,acc[0][2]); acc[0][3]=fmaf(av.x,bv.w,acc[0][3]);
      acc[1][0]=fmaf(av.y,bv.x,acc[1][0]); acc[1][1]=fmaf(av.y,bv.y,acc[1][1]);
      acc[1][2]=fmaf(av.y,bv.z,acc[1][2]); acc[1][3]=fmaf(av.y,bv.w,acc[1][3]);
      acc[2][0]=fmaf(av.z,bv.x,acc[2][0]); acc[2][1]=fmaf(av.z,bv.y,acc[2][1]);
      acc[2][2]=fmaf(av.z,bv.z,acc[2][2]); acc[2][3]=fmaf(av.z,bv.w,acc[2][3]);
      acc[3][0]=fmaf(av.w,bv.x,acc[3][0]); acc[3][1]=fmaf(av.w,bv.y,acc[3][1]);
      acc[3][2]=fmaf(av.w,bv.z,acc[3][2]); acc[3][3]=fmaf(av.w,bv.w,acc[3][3]);
    }
    if (tid < 64){
      float m = 0.f;
      for (int p = 0; p < 128; p++) m += tile[p*68 + tid];
      muacc[tid] += m;
    }
    __syncthreads();
  }
  if (tid < 64) atomicAdd(&g_stat3[tid], muacc[tid]);
#pragma unroll
  for (int r=0;r<4;r++)
#pragma unroll
    for (int q=0;q<4;q++)
      atomicAdd(&g_stat3[64 + (ti*4+r)*64 + (tj*4+q)], acc[r][q]);
}

// ---------------------------------------------------------------- layer-3 BN fold, 8-way split
// Block b computes channels [b*16, b*16+16) with the ORIGINAL per-channel
// partial-sum order (prt in {0,1}, i stride 2) — bit-exact vs single-block.
__global__ __launch_bounds__(256, 4) void k_fold3(const float* __restrict__ W3,
                                                  const float* __restrict__ g3,
                                                  const float* __restrict__ be3){
  __shared__ float s_l[64*65];
  __shared__ float w_l[16*65];
  __shared__ float mu[64];
  __shared__ float partl[32];
  const int tid = threadIdx.x;
  const int cb = blockIdx.x * 16;
  const float invP = 1.0f / (float)PTOT;
  for (int i = tid; i < 4096; i += 256) s_l[(i>>6)*65 + (i&63)] = g_stat3[64 + i] * invP;
  for (int i = tid; i < 16*64; i += 256) w_l[(i>>6)*65 + (i&63)] = W3[(cb + (i>>6))*64 + (i&63)];
  if (tid < 64) mu[tid] = g_stat3[tid] * invP;
  __syncthreads();
  if (tid < 32){
    const int cl = tid & 15, prt = tid >> 4;
    float q = 0.f;
    for (int i = prt; i < 64; i += 2){
      float wi = w_l[cl*65 + i];
      float r = 0.f;
      for (int j = 0; j < 64; j++)
        r += s_l[i*65 + j] * w_l[cl*65 + j];
      q += wi * r;
    }
    partl[tid] = q;
  }
  __syncthreads();
  if (tid < 16){
    const int cl = tid;
    const int c = cb + cl;
    float q = partl[cl] + partl[16 + cl];   // q(prt0) + q(prt1), original order
    float ml = 0.f;
    for (int j = 0; j < 64; j++) ml += w_l[cl*65 + j] * mu[j];
    float var = q - ml*ml;
    float inv = 1.0f / sqrtf(var + 1e-5f);
    float sc = g3[c] * inv;
    float tc = be3[c] - sc * ml;
    g_st3[c] = sc; g_st3[128 + c] = tc;
  }
}

// ---------------------------------------------------------------- final: layers 2-3 + maxpool
// Reads materialized h2 (coalesced); 2048 blocks x 4 groups each.
__global__ __launch_bounds__(256, 2) void k_final(const float* __restrict__ W2,
    const float* __restrict__ W3,
    float* __restrict__ out){
  __shared__ float s2v[64], t2v[64], s3v[128], t3v[128];
  __shared__ float h2t[32*68];
  __shared__ float h3t[32*68];
  __shared__ float mx[2][128];
  const int tid = threadIdx.x;
  const int g0 = blockIdx.x * 4;
  if (tid < 64){
    s2v[tid]=g_st2[tid]; t2v[tid]=g_st2[64+tid];
  }
  if (tid < 128){ s3v[tid]=g_st3[tid]; t3v[tid]=g_st3[128+tid]; }
  __syncthreads();
  for (int gi = 0; gi < 4; gi++){
    // stage h2 (32 x 64) — coalesced read of materialized values
    {
      const float* src = &g_h2[(size_t)(g0 + gi) * 32 * 64];
#pragma unroll
      for (int u = 0; u < 8; u++){
        int v = tid + u * 256;
        int kk = v >> 6, c = v & 63;
        h2t[kk*68 + c] = src[v];
      }
    }
    __syncthreads();
    // layer 2: thread owns channel c2, 8 k's
    {
      const int c2 = tid & 63, kq = tid >> 6;
      float wv2[64];
      const float4* wrow = (const float4*)(W2 + c2*64);
#pragma unroll
      for (int q = 0; q < 16; q++){
        float4 uv = wrow[q];
        wv2[q*4+0]=uv.x; wv2[q*4+1]=uv.y; wv2[q*4+2]=uv.z; wv2[q*4+3]=uv.w;
      }
#pragma unroll
      for (int k2 = 0; k2 < 8; k2++){
        int kk = kq*8 + k2;
        const float4* hr = (const float4*)&h2t[kk*68];
        float y = 0.f;
#pragma unroll
        for (int j4 = 0; j4 < 16; j4++){
          float4 hv = hr[j4];
          y = fmaf(wv2[j4*4+0], hv.x, y);
          y = fmaf(wv2[j4*4+1], hv.y, y);
          y = fmaf(wv2[j4*4+2], hv.z, y);
          y = fmaf(wv2[j4*4+3], hv.w, y);
        }
        h3t[kk*68 + c2] = fmaxf(fmaf(s2v[c2], y, t2v[c2]), 0.f);
      }
    }
    __syncthreads();
    // layer 3 + max over k
    {
      const int c3 = tid & 127, half = tid >> 7;
      float wv3[64];
      const float4* wrow = (const float4*)(W3 + c3*64);
#pragma unroll
      for (int q = 0; q < 16; q++){
        float4 uv = wrow[q];
        wv3[q*4+0]=uv.x; wv3[q*4+1]=uv.y; wv3[q*4+2]=uv.z; wv3[q*4+3]=uv.w;
      }
      float m = -1e30f;
#pragma unroll
      for (int k2 = 0; k2 < 16; k2++){
        int kk = half*16 + k2;
        const float4* hr = (const float4*)&h3t[kk*68];
        float y = 0.f;
#pragma unroll
        for (int j4 = 0; j4 < 16; j4++){
          float4 hv = hr[j4];
          y = fmaf(wv3[j4*4+0], hv.x, y);
          y = fmaf(wv3[j4*4+1], hv.y, y);
          y = fmaf(wv3[j4*4+2], hv.z, y);
          y = fmaf(wv3[j4*4+3], hv.w, y);
        }
        float h4 = fmaxf(fmaf(s3v[c3], y, t3v[c3]), 0.f);
        m = fmaxf(m, h4);
      }
      mx[half][c3] = m;
    }
    __syncthreads();
    if (tid < 128){
      float m = fmaxf(mx[0][tid], mx[1][tid]);
      out[24576 + ((g0 + gi) << 7) + tid] = m; // f32 feature output
    }
    __syncthreads();
  }
}

// ---------------------------------------------------------------- launch
extern "C" void kernel_launch(void* const* d_in, const int* in_sizes, int n_in,
                              void* d_out, int out_size, void* d_ws, size_t ws_size,
                              hipStream_t stream){
  const float* x   = (const float*)d_in[0];
  const float* W1  = (const float*)d_in[1];
  const float* g1  = (const float*)d_in[3];
  const float* be1 = (const float*)d_in[4];
  const float* W2  = (const float*)d_in[5];
  const float* g2  = (const float*)d_in[7];
  const float* be2 = (const float*)d_in[8];
  const float* W3  = (const float*)d_in[9];
  const float* g3  = (const float*)d_in[11];
  const float* be3 = (const float*)d_in[12];
  float* out = (float*)d_out;
  (void)d_ws; (void)ws_size; (void)in_sizes; (void)n_in; (void)out_size;

  k_fps<<<NB, 512, 0, stream>>>(x);
  k_ballq<<<(NB*NS)/4, 256, 0, stream>>>(x, out);
  k_stat1<<<256, 256, 0, stream>>>(x);
  k_stat2<<<256, 256, 0, stream>>>(x, W1, g1, be1);
  k_stat3<<<256, 256, 0, stream>>>(W2, g2, be2);
  k_fold3<<<8, 256, 0, stream>>>(W3, g3, be3);
  k_final<<<2048, 256, 0, stream>>>(W2, W3, out);
}